// Round 11
// baseline (98.424 us; speedup 1.0000x reference)
//
#include <hip/hip_runtime.h>
#include <hip/hip_bf16.h>

#define NSEQ 4096
#define FT 256
#define BK 64

typedef __attribute__((ext_vector_type(8))) short bf16x8;
typedef __attribute__((ext_vector_type(4))) float f32x4;

__device__ __forceinline__ ushort f2bf(float f) {
  __hip_bfloat16 h = __float2bfloat16(f);
  return *reinterpret_cast<const ushort*>(&h);
}

// XOR swizzle of 16B granules within a 128B row.
__device__ __forceinline__ int swz(int row, int byteInRow) {
  return row * 128 + (byteInRow ^ ((row & 7) << 4));
}

__device__ __forceinline__ void mma_step(const char* lAp, const char* lBp,
                                         int lane, int wm, int wn,
                                         f32x4 acc[2][4]) {
  const int r16 = lane & 15;
  const int g16 = (lane >> 4) * 16;
#pragma unroll
  for (int kk = 0; kk < 2; ++kk) {
    const int kb = kk * 64 + g16;
    bf16x8 a[2], b[4];
#pragma unroll
    for (int mi = 0; mi < 2; ++mi) {
      const int row = wm * 32 + mi * 16 + r16;
      a[mi] = *reinterpret_cast<const bf16x8*>(lAp + swz(row, kb));
    }
#pragma unroll
    for (int ni = 0; ni < 4; ++ni) {
      const int row = wn * 64 + ni * 16 + r16;
      b[ni] = *reinterpret_cast<const bf16x8*>(lBp + swz(row, kb));
    }
#pragma unroll
    for (int mi = 0; mi < 2; ++mi)
#pragma unroll
      for (int ni = 0; ni < 4; ++ni)
        acc[mi][ni] = __builtin_amdgcn_mfma_f32_16x16x32_bf16(a[mi], b[ni],
                                                             acc[mi][ni], 0, 0, 0);
  }
}

// ---------------- Kernel A (unchanged): hT[b][o][n] = (seq @ W^T + b) bf16 ----------------
__global__ __launch_bounds__(512) void linear_kernel(
    const float* __restrict__ seq, const float* __restrict__ W,
    const float* __restrict__ bias, ushort* __restrict__ hT) {
  __shared__ __align__(16) ushort lA[2][64 * 64];
  __shared__ __align__(16) ushort lB[2][256 * 64];

  const int tid = threadIdx.x;
  const int lane = tid & 63;
  const int wid = tid >> 6;
  const int wm = wid >> 2, wn = wid & 3;
  const int m0 = blockIdx.x * 64;

  const int ar = tid >> 4, ac = tid & 15;

  f32x4 rA[2];
  f32x4 rB[8];

  auto gload = [&](int t) {
    const int k0 = t * BK;
#pragma unroll
    for (int p = 0; p < 2; ++p)
      rA[p] = *reinterpret_cast<const f32x4*>(
          seq + (size_t)(m0 + ar + p * 32) * FT + k0 + ac * 4);
#pragma unroll
    for (int p = 0; p < 8; ++p)
      rB[p] = *reinterpret_cast<const f32x4*>(
          W + (size_t)(ar + p * 32) * FT + k0 + ac * 4);
  };
  auto lwrite = [&](int buf) {
    char* lAp = (char*)lA[buf];
    char* lBp = (char*)lB[buf];
#pragma unroll
    for (int p = 0; p < 2; ++p) {
      ushort4 u = make_ushort4(f2bf(rA[p][0]), f2bf(rA[p][1]), f2bf(rA[p][2]), f2bf(rA[p][3]));
      *reinterpret_cast<ushort4*>(lAp + swz(ar + p * 32, ac * 8)) = u;
    }
#pragma unroll
    for (int p = 0; p < 8; ++p) {
      ushort4 u = make_ushort4(f2bf(rB[p][0]), f2bf(rB[p][1]), f2bf(rB[p][2]), f2bf(rB[p][3]));
      *reinterpret_cast<ushort4*>(lBp + swz(ar + p * 32, ac * 8)) = u;
    }
  };

  f32x4 acc[2][4];
  const f32x4 zero = {0.f, 0.f, 0.f, 0.f};
#pragma unroll
  for (int mi = 0; mi < 2; ++mi)
#pragma unroll
    for (int ni = 0; ni < 4; ++ni) acc[mi][ni] = zero;

  gload(0);
  lwrite(0);
  const int NTA = FT / BK;  // 4
  for (int t = 0; t < NTA; ++t) {
    const int cur = t & 1;
    __syncthreads();
    if (t + 1 < NTA) gload(t + 1);
    mma_step((const char*)lA[cur], (const char*)lB[cur], lane, wm, wn, acc);
    if (t + 1 < NTA) lwrite(cur ^ 1);
  }

#pragma unroll
  for (int mi = 0; mi < 2; ++mi) {
    const int grow = m0 + wm * 32 + mi * 16 + ((lane >> 4) << 2);
    const int batch = grow >> 12;
    const int n = grow & (NSEQ - 1);
#pragma unroll
    for (int ni = 0; ni < 4; ++ni) {
      const int o = wn * 64 + ni * 16 + (lane & 15);
      const float bo = bias[o];
      ushort4 u;
      u.x = f2bf(acc[mi][ni][0] + bo);
      u.y = f2bf(acc[mi][ni][1] + bo);
      u.z = f2bf(acc[mi][ni][2] + bo);
      u.w = f2bf(acc[mi][ni][3] + bo);
      *reinterpret_cast<ushort4*>(hT + (size_t)(batch * FT + o) * NSEQ + n) = u;
    }
  }
}

// ---------------- Kernel B: out = PReLU(adj @ h), 2 blocks/CU ----------------
// BM=32, BN=256, BK=64. 512 thr = 8 waves (1x8 col-split, wave tile 32x32).
// Grid 512 = 2 independent blocks/CU: when one block drains at its barrier,
// the sibling's waves keep HBM/MFMA busy. LDS 72 KB/block. hT via glds
// (pre-swizzled source), dbuf; adj reg-staged in-body (no cross-iter
// liveness). Counted vmcnt(4) then vmcnt(0) at the barrier.
__global__ __launch_bounds__(512, 4) void bmm_prelu_kernel(
    const float* __restrict__ adj, const ushort* __restrict__ hT,
    const float* __restrict__ alphaP, float* __restrict__ out) {
  // [0,64K): lB[2] (256 rows x 128 B each); [64K,72K): lA[2] (32 rows x 128 B)
  __shared__ __align__(16) char smem[2 * 32768 + 2 * 4096];

  const int tid = threadIdx.x;
  const int lane = tid & 63;
  const int wid = tid >> 6;  // 0..7 = wave's 32-col group

  // XCD-contiguous remap (bijective: 512 = 8 * 64).
  const int bid = blockIdx.x;
  const int sbid = (bid & 7) * 64 + (bid >> 3);
  const int batch = sbid >> 7;       // 128 row-tiles per batch
  const int m0 = (sbid & 127) * 32;

  const float* adjB = adj + (size_t)batch * NSEQ * NSEQ + (size_t)m0 * NSEQ;
  const ushort* hTB = hT + (size_t)batch * FT * NSEQ;

  auto lB = [&](int i) -> char* { return smem + i * 32768; };
  auto lA = [&](int i) -> char* { return smem + 65536 + i * 4096; };

  const int ar = tid >> 4, ac = tid & 15;   // adj: row 0..31, granule 0..15
  const int brow = wid * 8 + (lane >> 3);   // hT row (+ p*64)
  const int bg = (lane & 7) ^ (lane >> 3);  // pre-swizzled source granule

  f32x4 rS;  // single in-body A staging reg (no cross-iteration liveness)

  f32x4 acc[2][2];
  const f32x4 zero = {0.f, 0.f, 0.f, 0.f};
#pragma unroll
  for (int mi = 0; mi < 2; ++mi)
#pragma unroll
    for (int ni = 0; ni < 2; ++ni) acc[mi][ni] = zero;

  auto issueA = [&](int t) {
    rS = *reinterpret_cast<const f32x4*>(adjB + (size_t)ar * NSEQ + t * BK + ac * 4);
  };
  auto issueB = [&](int t, int ib) {
    const int k0 = t * BK;
#pragma unroll
    for (int p = 0; p < 4; ++p) {
      const ushort* gp = hTB + (size_t)(p * 64 + brow) * NSEQ + k0 + bg * 8;
      char* lp = lB(ib) + p * 8192 + wid * 1024;  // wave-uniform; HW adds lane*16
      __builtin_amdgcn_global_load_lds(
          (const __attribute__((address_space(1))) void*)gp,
          (__attribute__((address_space(3))) void*)lp, 16, 0, 0);
    }
  };
  auto writeA = [&](int ia) {
    ushort4 u = make_ushort4(f2bf(rS[0]), f2bf(rS[1]), f2bf(rS[2]), f2bf(rS[3]));
    *reinterpret_cast<ushort4*>(lA(ia) + swz(ar, ac * 8)) = u;
  };
  auto mma8 = [&](const char* lAp, const char* lBp) {
    const int r16 = lane & 15;
    const int g16 = (lane >> 4) * 16;
#pragma unroll
    for (int kk = 0; kk < 2; ++kk) {
      const int kb = kk * 64 + g16;
      bf16x8 a[2], b[2];
#pragma unroll
      for (int mi = 0; mi < 2; ++mi)
        a[mi] = *reinterpret_cast<const bf16x8*>(lAp + swz(mi * 16 + r16, kb));
#pragma unroll
      for (int ni = 0; ni < 2; ++ni)
        b[ni] = *reinterpret_cast<const bf16x8*>(
            lBp + swz(wid * 32 + ni * 16 + r16, kb));
#pragma unroll
      for (int mi = 0; mi < 2; ++mi)
#pragma unroll
        for (int ni = 0; ni < 2; ++ni)
          acc[mi][ni] = __builtin_amdgcn_mfma_f32_16x16x32_bf16(
              a[mi], b[ni], acc[mi][ni], 0, 0, 0);
    }
  };

  // Prologue: stage tile 0.
  issueA(0);
  issueB(0, 0);
  asm volatile("s_waitcnt vmcnt(4)" ::: "memory");  // A0 regs ready
  writeA(0);
  asm volatile("s_waitcnt vmcnt(0) lgkmcnt(0)" ::: "memory");  // B0 in LDS
  __builtin_amdgcn_s_barrier();
  __builtin_amdgcn_sched_barrier(0);

  // body(t, cur): issue tile t+1 into bufs cur^1; compute tile t from cur.
  auto body = [&](int t, int cur) {
    issueA(t + 1);                 // 1 VM
    issueB(t + 1, cur ^ 1);        // 4 VM
    __builtin_amdgcn_s_setprio(1);
    mma8(lA(cur), lB(cur));
    __builtin_amdgcn_s_setprio(0);
    asm volatile("s_waitcnt vmcnt(4)" ::: "memory");  // A(t+1) regs ready
    writeA(cur ^ 1);
    asm volatile("s_waitcnt vmcnt(0) lgkmcnt(0)" ::: "memory");
    __builtin_amdgcn_s_barrier();
    __builtin_amdgcn_sched_barrier(0);
  };

  // t = 0..61 in pairs, then t = 62, then final compute of tile 63.
  for (int j = 0; j < 31; ++j) {
    body(2 * j, 0);
    body(2 * j + 1, 1);
  }
  body(62, 0);
  __builtin_amdgcn_s_setprio(1);
  mma8(lA(1), lB(1));
  __builtin_amdgcn_s_setprio(0);

  // Epilogue: PReLU -> LDS overlay (padded pitch) -> coalesced rows.
  const float alpha = *alphaP;
  __syncthreads();
  float* lo = (float*)smem;  // 32 x 264 f32 = 33.8 KB (fits in 72 KB)
  const int PITCH = 264;
#pragma unroll
  for (int mi = 0; mi < 2; ++mi) {
    const int rbase = mi * 16 + ((lane >> 4) << 2);
#pragma unroll
    for (int ni = 0; ni < 2; ++ni) {
      const int o = wid * 32 + ni * 16 + (lane & 15);
#pragma unroll
      for (int j = 0; j < 4; ++j) {
        float v = acc[mi][ni][j];
        v = v > 0.f ? v : alpha * v;
        lo[(rbase + j) * PITCH + o] = v;
      }
    }
  }
  __syncthreads();
  float* outB = out + ((size_t)batch * NSEQ + m0) * FT;
  const int r = tid >> 4, c16 = tid & 15;  // 32 rows, 16 threads/row
#pragma unroll
  for (int k = 0; k < 4; ++k) {            // 4 granules each -> 256 floats/row
    const int g = c16 + k * 16;
    f32x4 v = *reinterpret_cast<const f32x4*>(lo + r * PITCH + g * 4);
    __builtin_nontemporal_store(v, reinterpret_cast<f32x4*>(outB + (size_t)r * FT + g * 4));
  }
}

extern "C" void kernel_launch(void* const* d_in, const int* in_sizes, int n_in,
                              void* d_out, int out_size, void* d_ws, size_t ws_size,
                              hipStream_t stream) {
  const float* seq = (const float*)d_in[0];
  const float* adj = (const float*)d_in[1];
  const float* W = (const float*)d_in[2];
  const float* bias = (const float*)d_in[3];
  const float* alpha = (const float*)d_in[4];
  float* out = (float*)d_out;
  ushort* hT = (ushort*)d_ws;  // [4][256][4096] bf16 = 8 MB

  linear_kernel<<<256, 512, 0, stream>>>(seq, W, bias, hT);
  bmm_prelu_kernel<<<512, 512, 0, stream>>>(adj, hT, alpha, out);
}

// Round 12
// 85.302 us; speedup vs baseline: 1.1538x; 1.1538x over previous
//
#include <hip/hip_runtime.h>
#include <hip/hip_bf16.h>

#define NSEQ 4096
#define FT 256
#define BK 64
#define BKB 128
#define NTB (NSEQ / BKB)  // 32

typedef __attribute__((ext_vector_type(8))) short bf16x8;
typedef __attribute__((ext_vector_type(4))) float f32x4;

__device__ __forceinline__ ushort f2bf(float f) {
  __hip_bfloat16 h = __float2bfloat16(f);
  return *reinterpret_cast<const ushort*>(&h);
}

// XOR swizzle of 16B granules within a 128B row (kernel A staging).
__device__ __forceinline__ int swz(int row, int byteInRow) {
  return row * 128 + (byteInRow ^ ((row & 7) << 4));
}

__device__ __forceinline__ void mma_step(const char* lAp, const char* lBp,
                                         int lane, int wm, int wn,
                                         f32x4 acc[2][4]) {
  const int r16 = lane & 15;
  const int g16 = (lane >> 4) * 16;
#pragma unroll
  for (int kk = 0; kk < 2; ++kk) {
    const int kb = kk * 64 + g16;
    bf16x8 a[2], b[4];
#pragma unroll
    for (int mi = 0; mi < 2; ++mi) {
      const int row = wm * 32 + mi * 16 + r16;
      a[mi] = *reinterpret_cast<const bf16x8*>(lAp + swz(row, kb));
    }
#pragma unroll
    for (int ni = 0; ni < 4; ++ni) {
      const int row = wn * 64 + ni * 16 + r16;
      b[ni] = *reinterpret_cast<const bf16x8*>(lBp + swz(row, kb));
    }
#pragma unroll
    for (int mi = 0; mi < 2; ++mi)
#pragma unroll
      for (int ni = 0; ni < 4; ++ni)
        acc[mi][ni] = __builtin_amdgcn_mfma_f32_16x16x32_bf16(a[mi], b[ni],
                                                             acc[mi][ni], 0, 0, 0);
  }
}

// ---------------- Kernel A (unchanged): hT[b][o][n] = (seq @ W^T + b) bf16 ----------------
__global__ __launch_bounds__(512) void linear_kernel(
    const float* __restrict__ seq, const float* __restrict__ W,
    const float* __restrict__ bias, ushort* __restrict__ hT) {
  __shared__ __align__(16) ushort lA[2][64 * 64];
  __shared__ __align__(16) ushort lB[2][256 * 64];

  const int tid = threadIdx.x;
  const int lane = tid & 63;
  const int wid = tid >> 6;
  const int wm = wid >> 2, wn = wid & 3;
  const int m0 = blockIdx.x * 64;

  const int ar = tid >> 4, ac = tid & 15;

  f32x4 rA[2];
  f32x4 rB[8];

  auto gload = [&](int t) {
    const int k0 = t * BK;
#pragma unroll
    for (int p = 0; p < 2; ++p)
      rA[p] = *reinterpret_cast<const f32x4*>(
          seq + (size_t)(m0 + ar + p * 32) * FT + k0 + ac * 4);
#pragma unroll
    for (int p = 0; p < 8; ++p)
      rB[p] = *reinterpret_cast<const f32x4*>(
          W + (size_t)(ar + p * 32) * FT + k0 + ac * 4);
  };
  auto lwrite = [&](int buf) {
    char* lAp = (char*)lA[buf];
    char* lBp = (char*)lB[buf];
#pragma unroll
    for (int p = 0; p < 2; ++p) {
      ushort4 u = make_ushort4(f2bf(rA[p][0]), f2bf(rA[p][1]), f2bf(rA[p][2]), f2bf(rA[p][3]));
      *reinterpret_cast<ushort4*>(lAp + swz(ar + p * 32, ac * 8)) = u;
    }
#pragma unroll
    for (int p = 0; p < 8; ++p) {
      ushort4 u = make_ushort4(f2bf(rB[p][0]), f2bf(rB[p][1]), f2bf(rB[p][2]), f2bf(rB[p][3]));
      *reinterpret_cast<ushort4*>(lBp + swz(ar + p * 32, ac * 8)) = u;
    }
  };

  f32x4 acc[2][4];
  const f32x4 zero = {0.f, 0.f, 0.f, 0.f};
#pragma unroll
  for (int mi = 0; mi < 2; ++mi)
#pragma unroll
    for (int ni = 0; ni < 4; ++ni) acc[mi][ni] = zero;

  gload(0);
  lwrite(0);
  const int NTA = FT / BK;  // 4
  for (int t = 0; t < NTA; ++t) {
    const int cur = t & 1;
    __syncthreads();
    if (t + 1 < NTA) gload(t + 1);
    mma_step((const char*)lA[cur], (const char*)lB[cur], lane, wm, wn, acc);
    if (t + 1 < NTA) lwrite(cur ^ 1);
  }

#pragma unroll
  for (int mi = 0; mi < 2; ++mi) {
    const int grow = m0 + wm * 32 + mi * 16 + ((lane >> 4) << 2);
    const int batch = grow >> 12;
    const int n = grow & (NSEQ - 1);
#pragma unroll
    for (int ni = 0; ni < 4; ++ni) {
      const int o = wn * 64 + ni * 16 + (lane & 15);
      const float bo = bias[o];
      ushort4 u;
      u.x = f2bf(acc[mi][ni][0] + bo);
      u.y = f2bf(acc[mi][ni][1] + bo);
      u.z = f2bf(acc[mi][ni][2] + bo);
      u.w = f2bf(acc[mi][ni][3] + bo);
      *reinterpret_cast<ushort4*>(hT + (size_t)(batch * FT + o) * NSEQ + n) = u;
    }
  }
}

// ---------------- Kernel B: out = PReLU(adj @ h), phase-pipelined, never-drain ----------------
// BM=64, BN=256, BKB=128. Grid 256 (1 blk/CU), 512 thr (8 waves 2x4).
// B (hT) staged per 64-k HALF into a 4-slot ring (4 x 32 KB); A (adj) staged
// per 128-k tile into 2 bufs (2 x 16 KB). LDS = 160 KB exactly. Per phase:
// issue one future B-half (4 glds) + compute current half (16 MFMA). Counted
// waits only: vmcnt(8) at even-phase end, vmcnt(4) at odd-phase end -- the
// memory pipe NEVER drains to 0 until the tail (T3+T4).
__global__ __launch_bounds__(512) void bmm_prelu_kernel(
    const float* __restrict__ adj, const ushort* __restrict__ hT,
    const float* __restrict__ alphaP, float* __restrict__ out) {
  __shared__ __align__(16) char smem[4 * 32768 + 2 * 16384];  // ring[4] | lA[2]

  const int tid = threadIdx.x;
  const int lane = tid & 63;
  const int wid = tid >> 6;
  const int wm = wid >> 2, wn = wid & 3;

  // XCD-contiguous remap (bijective: 256 = 8 * 32).
  const int bid = blockIdx.x;
  const int sbid = (bid & 7) * 32 + (bid >> 3);
  const int batch = sbid >> 6;
  const int m0 = (sbid & 63) * 64;

  const float* adjB = adj + (size_t)batch * NSEQ * NSEQ + (size_t)m0 * NSEQ;
  const ushort* hTB = hT + (size_t)batch * FT * NSEQ;

  auto ring = [&](int i) -> char* { return smem + i * 32768; };
  auto lA = [&](int i) -> char* { return smem + 131072 + i * 16384; };

  // B-half staging geometry (R7-proven): 128B rows, 8 rows per glds.
  const int br = lane >> 3;                // row-in-group 0..7
  const int bgr = (lane & 7) ^ br;         // pre-swizzled source granule
  // adj staging geometry (R9-proven): row 0..63, 16 floats per thread.
  const int arow = tid >> 3, ac = tid & 7;

  f32x4 rS[4];

  f32x4 acc[2][4];
  const f32x4 zero = {0.f, 0.f, 0.f, 0.f};
#pragma unroll
  for (int mi = 0; mi < 2; ++mi)
#pragma unroll
    for (int ni = 0; ni < 4; ++ni) acc[mi][ni] = zero;

  auto issueA = [&](int t) {
    const int k0 = t * BKB;
#pragma unroll
    for (int q = 0; q < 4; ++q)
      rS[q] = *reinterpret_cast<const f32x4*>(
          adjB + (size_t)arow * NSEQ + k0 + ac * 16 + q * 4);
  };
  auto issueBh = [&](int t, int h, int s) {  // one 64-k half: 4 glds/thread
    const int k0 = t * BKB + h * 64;
#pragma unroll
    for (int p = 0; p < 4; ++p) {
      const ushort* gp =
          hTB + (size_t)(p * 64 + wid * 8 + br) * NSEQ + k0 + bgr * 8;
      char* lp = ring(s) + p * 8192 + wid * 1024;  // wave-uniform; HW +lane*16
      __builtin_amdgcn_global_load_lds(
          (const __attribute__((address_space(1))) void*)gp,
          (__attribute__((address_space(3))) void*)lp, 16, 0, 0);
    }
  };
  auto writeA = [&](int ia) {  // R9-verified granule map, 256B rows
    char* lAp = lA(ia);
    const int half = ac >> 2;
#pragma unroll
    for (int q = 0; q < 4; ++q) {
      ushort4 u = make_ushort4(f2bf(rS[q][0]), f2bf(rS[q][1]),
                               f2bf(rS[q][2]), f2bf(rS[q][3]));
      const int gih = (((ac & 3) * 2 + (q >> 1)) ^ (arow & 7));
      *reinterpret_cast<ushort4*>(lAp + arow * 256 + half * 128 + gih * 16 +
                                  (q & 1) * 8) = u;
    }
  };
  auto compute_half = [&](int h, const char* lAp, const char* lBp) {
    const int r16 = lane & 15;
    const int sub = lane >> 4;
#pragma unroll
    for (int kk2 = 0; kk2 < 2; ++kk2) {
      const int gih = ((kk2 * 4 + sub) ^ (r16 & 7));
      bf16x8 a[2], b[4];
#pragma unroll
      for (int mi = 0; mi < 2; ++mi)
        a[mi] = *reinterpret_cast<const bf16x8*>(
            lAp + (wm * 32 + mi * 16 + r16) * 256 + h * 128 + gih * 16);
#pragma unroll
      for (int ni = 0; ni < 4; ++ni)
        b[ni] = *reinterpret_cast<const bf16x8*>(
            lBp + (wn * 64 + ni * 16 + r16) * 128 + gih * 16);
#pragma unroll
      for (int mi = 0; mi < 2; ++mi)
#pragma unroll
        for (int ni = 0; ni < 4; ++ni)
          acc[mi][ni] = __builtin_amdgcn_mfma_f32_16x16x32_bf16(
              a[mi], b[ni], acc[mi][ni], 0, 0, 0);
    }
  };

  // Prologue: queue [B(0,k0) 4][A(0) 4][B(0,k1) 4]; vmcnt(4) retires first 8.
  issueBh(0, 0, 0);
  issueA(0);
  issueBh(0, 1, 1);
  asm volatile("s_waitcnt vmcnt(4)" ::: "memory");
  writeA(0);
  asm volatile("s_waitcnt lgkmcnt(0)" ::: "memory");
  __builtin_amdgcn_s_barrier();
  __builtin_amdgcn_sched_barrier(0);

  // body(t): even phase computes ring[s0]=B(t,k0); odd computes ring[s1].
  // Even end: vmcnt(8) retires B(t,k1), leaves [B(t+1,k0),A(t+1)] = 8.
  // Odd end:  vmcnt(4) retires B(t+1,k0)+A(t+1), leaves [B(t+1,k1)] = 4.
  auto body = [&](int t, int cur, int s0, int s1, int sI0, int sI1) {
    // ---- even phase ----
    issueBh(t + 1, 0, sI0);
    issueA(t + 1);
    __builtin_amdgcn_s_setprio(1);
    compute_half(0, lA(cur), ring(s0));
    __builtin_amdgcn_s_setprio(0);
    asm volatile("s_waitcnt vmcnt(8)" ::: "memory");
    __builtin_amdgcn_s_barrier();
    __builtin_amdgcn_sched_barrier(0);
    // ---- odd phase ----
    issueBh(t + 1, 1, sI1);
    __builtin_amdgcn_s_setprio(1);
    compute_half(1, lA(cur), ring(s1));
    __builtin_amdgcn_s_setprio(0);
    asm volatile("s_waitcnt vmcnt(4)" ::: "memory");
    writeA(cur ^ 1);
    asm volatile("s_waitcnt lgkmcnt(0)" ::: "memory");
    __builtin_amdgcn_s_barrier();
    __builtin_amdgcn_sched_barrier(0);
  };

  // t = 0..30 (31 bodies, period-2 static slot parity), then tail t = 31.
  for (int j = 0; j < 15; ++j) {
    body(2 * j, 0, 0, 1, 2, 3);
    body(2 * j + 1, 1, 2, 3, 0, 1);
  }
  body(30, 0, 0, 1, 2, 3);
  {  // tail: tile 31 (cur=1, slots 2,3). In flight: B(31,k1) only.
    __builtin_amdgcn_s_setprio(1);
    compute_half(0, lA(1), ring(2));
    __builtin_amdgcn_s_setprio(0);
    asm volatile("s_waitcnt vmcnt(0)" ::: "memory");
    __builtin_amdgcn_s_barrier();
    __builtin_amdgcn_sched_barrier(0);
    __builtin_amdgcn_s_setprio(1);
    compute_half(1, lA(1), ring(3));
    __builtin_amdgcn_s_setprio(0);
  }

  // Epilogue: PReLU -> LDS overlay (padded pitch) -> coalesced rows.
  const float alpha = *alphaP;
  __syncthreads();
  float* lo = (float*)smem;  // 64 x 264 f32 = 66 KB
  const int PITCH = 264;
#pragma unroll
  for (int mi = 0; mi < 2; ++mi) {
    const int rbase = wm * 32 + mi * 16 + ((lane >> 4) << 2);
#pragma unroll
    for (int ni = 0; ni < 4; ++ni) {
      const int o = wn * 64 + ni * 16 + (lane & 15);
#pragma unroll
      for (int j = 0; j < 4; ++j) {
        float v = acc[mi][ni][j];
        v = v > 0.f ? v : alpha * v;
        lo[(rbase + j) * PITCH + o] = v;
      }
    }
  }
  __syncthreads();
  float* outB = out + ((size_t)batch * NSEQ + m0) * FT;
  const int r = tid >> 3, c8 = tid & 7;
#pragma unroll
  for (int k = 0; k < 8; ++k) {
    const int g = c8 + k * 8;
    f32x4 v = *reinterpret_cast<const f32x4*>(lo + r * PITCH + g * 4);
    __builtin_nontemporal_store(v, reinterpret_cast<f32x4*>(outB + (size_t)r * FT + g * 4));
  }
}

extern "C" void kernel_launch(void* const* d_in, const int* in_sizes, int n_in,
                              void* d_out, int out_size, void* d_ws, size_t ws_size,
                              hipStream_t stream) {
  const float* seq = (const float*)d_in[0];
  const float* adj = (const float*)d_in[1];
  const float* W = (const float*)d_in[2];
  const float* bias = (const float*)d_in[3];
  const float* alpha = (const float*)d_in[4];
  float* out = (float*)d_out;
  ushort* hT = (ushort*)d_ws;  // [4][256][4096] bf16 = 8 MB

  linear_kernel<<<256, 512, 0, stream>>>(seq, W, bias, hT);
  bmm_prelu_kernel<<<256, 512, 0, stream>>>(adj, hT, alpha, out);
}

// Round 13
// 83.262 us; speedup vs baseline: 1.1821x; 1.0245x over previous
//
#include <hip/hip_runtime.h>
#include <hip/hip_bf16.h>

#define NSEQ 4096
#define FT 256
#define BK 64
#define BKB 128
#define NTB (NSEQ / BKB)  // 32

typedef __attribute__((ext_vector_type(8))) short bf16x8;
typedef __attribute__((ext_vector_type(4))) float f32x4;

__device__ __forceinline__ ushort f2bf(float f) {
  __hip_bfloat16 h = __float2bfloat16(f);
  return *reinterpret_cast<const ushort*>(&h);
}

// XOR swizzle of 16B granules within a 128B row.
__device__ __forceinline__ int swz(int row, int byteInRow) {
  return row * 128 + (byteInRow ^ ((row & 7) << 4));
}

__device__ __forceinline__ void mma_step(const char* lAp, const char* lBp,
                                         int lane, int wm, int wn,
                                         f32x4 acc[2][4]) {
  const int r16 = lane & 15;
  const int g16 = (lane >> 4) * 16;
#pragma unroll
  for (int kk = 0; kk < 2; ++kk) {
    const int kb = kk * 64 + g16;
    bf16x8 a[2], b[4];
#pragma unroll
    for (int mi = 0; mi < 2; ++mi) {
      const int row = wm * 32 + mi * 16 + r16;
      a[mi] = *reinterpret_cast<const bf16x8*>(lAp + swz(row, kb));
    }
#pragma unroll
    for (int ni = 0; ni < 4; ++ni) {
      const int row = wn * 64 + ni * 16 + r16;
      b[ni] = *reinterpret_cast<const bf16x8*>(lBp + swz(row, kb));
    }
#pragma unroll
    for (int mi = 0; mi < 2; ++mi)
#pragma unroll
      for (int ni = 0; ni < 4; ++ni)
        acc[mi][ni] = __builtin_amdgcn_mfma_f32_16x16x32_bf16(a[mi], b[ni],
                                                             acc[mi][ni], 0, 0, 0);
  }
}

// ---------------- Kernel A: hT[b][o][n] = (seq @ W^T + b) bf16 ----------------
// New epilogue: LDS transpose -> coalesced 16B hT stores (was 8B @ 8KB stride).
__global__ __launch_bounds__(512) void linear_kernel(
    const float* __restrict__ seq, const float* __restrict__ W,
    const float* __restrict__ bias, ushort* __restrict__ hT) {
  __shared__ __align__(16) ushort lA[2][64 * 64];
  __shared__ __align__(16) ushort lB[2][256 * 64];

  const int tid = threadIdx.x;
  const int lane = tid & 63;
  const int wid = tid >> 6;
  const int wm = wid >> 2, wn = wid & 3;
  const int m0 = blockIdx.x * 64;

  const int ar = tid >> 4, ac = tid & 15;

  f32x4 rA[2];
  f32x4 rB[8];

  auto gload = [&](int t) {
    const int k0 = t * BK;
#pragma unroll
    for (int p = 0; p < 2; ++p)
      rA[p] = *reinterpret_cast<const f32x4*>(
          seq + (size_t)(m0 + ar + p * 32) * FT + k0 + ac * 4);
#pragma unroll
    for (int p = 0; p < 8; ++p)
      rB[p] = *reinterpret_cast<const f32x4*>(
          W + (size_t)(ar + p * 32) * FT + k0 + ac * 4);
  };
  auto lwrite = [&](int buf) {
    char* lAp = (char*)lA[buf];
    char* lBp = (char*)lB[buf];
#pragma unroll
    for (int p = 0; p < 2; ++p) {
      ushort4 u = make_ushort4(f2bf(rA[p][0]), f2bf(rA[p][1]), f2bf(rA[p][2]), f2bf(rA[p][3]));
      *reinterpret_cast<ushort4*>(lAp + swz(ar + p * 32, ac * 8)) = u;
    }
#pragma unroll
    for (int p = 0; p < 8; ++p) {
      ushort4 u = make_ushort4(f2bf(rB[p][0]), f2bf(rB[p][1]), f2bf(rB[p][2]), f2bf(rB[p][3]));
      *reinterpret_cast<ushort4*>(lBp + swz(ar + p * 32, ac * 8)) = u;
    }
  };

  f32x4 acc[2][4];
  const f32x4 zero = {0.f, 0.f, 0.f, 0.f};
#pragma unroll
  for (int mi = 0; mi < 2; ++mi)
#pragma unroll
    for (int ni = 0; ni < 4; ++ni) acc[mi][ni] = zero;

  gload(0);
  lwrite(0);
  const int NTA = FT / BK;  // 4
  for (int t = 0; t < NTA; ++t) {
    const int cur = t & 1;
    __syncthreads();
    if (t + 1 < NTA) gload(t + 1);
    mma_step((const char*)lA[cur], (const char*)lB[cur], lane, wm, wn, acc);
    if (t + 1 < NTA) lwrite(cur ^ 1);
  }

  // Epilogue: +bias, bf16, transpose via LDS overlay, coalesced stores.
  __syncthreads();
  ushort* lT = (ushort*)&lB[0][0];  // [256][72] ushort = 36 KB overlay
  const int TP = 72;
#pragma unroll
  for (int mi = 0; mi < 2; ++mi) {
    const int rbase = wm * 32 + mi * 16 + ((lane >> 4) << 2);
#pragma unroll
    for (int ni = 0; ni < 4; ++ni) {
      const int o = wn * 64 + ni * 16 + (lane & 15);
      const float bo = bias[o];
      ushort4 u;
      u.x = f2bf(acc[mi][ni][0] + bo);
      u.y = f2bf(acc[mi][ni][1] + bo);
      u.z = f2bf(acc[mi][ni][2] + bo);
      u.w = f2bf(acc[mi][ni][3] + bo);
      *reinterpret_cast<ushort4*>(&lT[o * TP + rbase]) = u;
    }
  }
  __syncthreads();
  const int batch = (blockIdx.x * 64) >> 12;   // blocks never straddle a batch
  const int n0 = (blockIdx.x * 64) & (NSEQ - 1);
  const int o = tid >> 1, hf = tid & 1;        // 256 o-rows x 2 halves
  ushort* dst = hT + ((size_t)(batch * FT + o)) * NSEQ + n0 + hf * 32;
#pragma unroll
  for (int k = 0; k < 4; ++k) {  // 4 x 16B contiguous per thread
    uint4 v = *reinterpret_cast<const uint4*>(&lT[o * TP + hf * 32 + k * 8]);
    *reinterpret_cast<uint4*>(dst + k * 8) = v;
  }
}

// ---------------- Kernel B (R9 verbatim): out = PReLU(adj @ h), BK=128 ----------------
__global__ __launch_bounds__(512) void bmm_prelu_kernel(
    const float* __restrict__ adj, const ushort* __restrict__ hT,
    const float* __restrict__ alphaP, float* __restrict__ out) {
  __shared__ __align__(16) char smem[2 * 65536 + 2 * 16384];  // lB[2] | lA[2]

  const int tid = threadIdx.x;
  const int lane = tid & 63;
  const int wid = tid >> 6;
  const int wm = wid >> 2, wn = wid & 3;

  const int bid = blockIdx.x;
  const int sbid = (bid & 7) * 32 + (bid >> 3);
  const int batch = sbid >> 6;
  const int m0 = (sbid & 63) * 64;

  const float* adjB = adj + (size_t)batch * NSEQ * NSEQ + (size_t)m0 * NSEQ;
  const ushort* hTB = hT + (size_t)batch * FT * NSEQ;

  auto lB = [&](int i) -> char* { return smem + i * 65536; };
  auto lA = [&](int i) -> char* { return smem + 131072 + i * 16384; };

  const int arow = tid >> 3, ac = tid & 7;
  const int bro = (lane >> 4);
  const int bhalf = (lane >> 3) & 1;
  f32x4 rS[4];

  f32x4 acc[2][4];
  const f32x4 zero = {0.f, 0.f, 0.f, 0.f};
#pragma unroll
  for (int mi = 0; mi < 2; ++mi)
#pragma unroll
    for (int ni = 0; ni < 4; ++ni) acc[mi][ni] = zero;

  auto issueA = [&](int t) {
    const int k0 = t * BKB;
#pragma unroll
    for (int q = 0; q < 4; ++q)
      rS[q] = *reinterpret_cast<const f32x4*>(
          adjB + (size_t)arow * NSEQ + k0 + ac * 16 + q * 4);
  };
  auto issueB = [&](int t, int ib) {
    const int k0 = t * BKB;
#pragma unroll
    for (int p = 0; p < 8; ++p) {
      const int grow = wid * 32 + p * 4 + bro;
      const int gsrc = (lane & 7) ^ (((p & 1) * 4 + bro) & 7);
      const ushort* gp = hTB + (size_t)grow * NSEQ + k0 + bhalf * 64 + gsrc * 8;
      char* lp = lB(ib) + wid * 8192 + p * 1024;
      __builtin_amdgcn_global_load_lds(
          (const __attribute__((address_space(1))) void*)gp,
          (__attribute__((address_space(3))) void*)lp, 16, 0, 0);
    }
  };
  auto writeA = [&](int ia) {
    char* lAp = lA(ia);
    const int half = ac >> 2;
#pragma unroll
    for (int q = 0; q < 4; ++q) {
      ushort4 u = make_ushort4(f2bf(rS[q][0]), f2bf(rS[q][1]),
                               f2bf(rS[q][2]), f2bf(rS[q][3]));
      const int gih = (((ac & 3) * 2 + (q >> 1)) ^ (arow & 7));
      *reinterpret_cast<ushort4*>(lAp + arow * 256 + half * 128 + gih * 16 +
                                  (q & 1) * 8) = u;
    }
  };
  auto mma32 = [&](const char* lAp, const char* lBp) {
    const int r16 = lane & 15;
    const int sub = lane >> 4;
#pragma unroll
    for (int kk = 0; kk < 4; ++kk) {
      const int half = kk >> 1;
      const int gih = (((kk & 1) * 4 + sub) ^ (r16 & 7));
      const int bofs = half * 128 + gih * 16;
      bf16x8 a[2], b[4];
#pragma unroll
      for (int mi = 0; mi < 2; ++mi) {
        const int row = wm * 32 + mi * 16 + r16;
        a[mi] = *reinterpret_cast<const bf16x8*>(lAp + row * 256 + bofs);
      }
#pragma unroll
      for (int ni = 0; ni < 4; ++ni) {
        const int row = wn * 64 + ni * 16 + r16;
        b[ni] = *reinterpret_cast<const bf16x8*>(lBp + row * 256 + bofs);
      }
#pragma unroll
      for (int mi = 0; mi < 2; ++mi)
#pragma unroll
        for (int ni = 0; ni < 4; ++ni)
          acc[mi][ni] = __builtin_amdgcn_mfma_f32_16x16x32_bf16(
              a[mi], b[ni], acc[mi][ni], 0, 0, 0);
    }
  };

  issueA(0);
  __builtin_amdgcn_sched_barrier(0);
  issueB(0, 0);
  __builtin_amdgcn_sched_barrier(0);
  asm volatile("s_waitcnt vmcnt(8)" ::: "memory");
  __builtin_amdgcn_sched_barrier(0);
  writeA(0);
  asm volatile("s_waitcnt vmcnt(0) lgkmcnt(0)" ::: "memory");
  __builtin_amdgcn_s_barrier();
  __builtin_amdgcn_sched_barrier(0);

  auto body = [&](int t, int cur) {
    issueA(t + 1);
    __builtin_amdgcn_sched_barrier(0);
    issueB(t + 1, cur ^ 1);
    __builtin_amdgcn_sched_barrier(0);
    __builtin_amdgcn_s_setprio(1);
    mma32(lA(cur), lB(cur));
    __builtin_amdgcn_s_setprio(0);
    asm volatile("s_waitcnt vmcnt(8)" ::: "memory");
    __builtin_amdgcn_sched_barrier(0);
    writeA(cur ^ 1);
    asm volatile("s_waitcnt vmcnt(0) lgkmcnt(0)" ::: "memory");
    __builtin_amdgcn_s_barrier();
    __builtin_amdgcn_sched_barrier(0);
  };

  for (int j = 0; j < 15; ++j) {
    body(2 * j, 0);
    body(2 * j + 1, 1);
  }
  body(30, 0);
  __builtin_amdgcn_s_setprio(1);
  mma32(lA(1), lB(1));
  __builtin_amdgcn_s_setprio(0);

  const float alpha = *alphaP;
  __syncthreads();
  float* lo = (float*)smem;
  const int PITCH = 264;
#pragma unroll
  for (int mi = 0; mi < 2; ++mi) {
    const int rbase = wm * 32 + mi * 16 + ((lane >> 4) << 2);
#pragma unroll
    for (int ni = 0; ni < 4; ++ni) {
      const int o = wn * 64 + ni * 16 + (lane & 15);
#pragma unroll
      for (int j = 0; j < 4; ++j) {
        float v = acc[mi][ni][j];
        v = v > 0.f ? v : alpha * v;
        lo[(rbase + j) * PITCH + o] = v;
      }
    }
  }
  __syncthreads();
  float* outB = out + ((size_t)batch * NSEQ + m0) * FT;
  const int r = tid >> 3, c8 = tid & 7;
#pragma unroll
  for (int k = 0; k < 8; ++k) {
    const int g = c8 + k * 8;
    f32x4 v = *reinterpret_cast<const f32x4*>(lo + r * PITCH + g * 4);
    __builtin_nontemporal_store(v, reinterpret_cast<f32x4*>(outB + (size_t)r * FT + g * 4));
  }
}

extern "C" void kernel_launch(void* const* d_in, const int* in_sizes, int n_in,
                              void* d_out, int out_size, void* d_ws, size_t ws_size,
                              hipStream_t stream) {
  const float* seq = (const float*)d_in[0];
  const float* adj = (const float*)d_in[1];
  const float* W = (const float*)d_in[2];
  const float* bias = (const float*)d_in[3];
  const float* alpha = (const float*)d_in[4];
  float* out = (float*)d_out;
  ushort* hT = (ushort*)d_ws;  // [4][256][4096] bf16 = 8 MB

  linear_kernel<<<256, 512, 0, stream>>>(seq, W, bias, hT);
  bmm_prelu_kernel<<<256, 512, 0, stream>>>(adj, hT, alpha, out);
}